// Round 1
// baseline (386.240 us; speedup 1.0000x reference)
//
#include <hip/hip_runtime.h>

#define IMG    224
#define NPIX   (IMG * IMG)       // 50176
#define NELEM  (NPIX * 3)        // 150528
#define KSEL   12544             // 0.25 * IMG * IMG
#define NBINS  4096
#define MAXCAND 2048
#define NMASKW (NPIX / 32)       // 1568 words
#define NVEC   (NELEM / 4)       // 37632 float4 per sample
#define BLOCK  1024

__global__ __launch_bounds__(BLOCK) void masked_model_kernel(
    const float* __restrict__ data,
    const float* __restrict__ grad,
    float* __restrict__ out)
{
    const int b   = blockIdx.x;
    const int tid = threadIdx.x;

    const float* g = grad + (size_t)b * NELEM;
    const float* d = data + (size_t)b * NELEM;
    float*       o = out  + (size_t)b * NELEM;

    __shared__ unsigned int hist[NBINS];
    __shared__ unsigned int suffixP[BLOCK + 1];
    __shared__ unsigned int mask[NMASKW];
    __shared__ unsigned int candkey[MAXCAND];
    __shared__ unsigned int candidx[MAXCAND];
    __shared__ unsigned int candcnt;
    __shared__ int sB1;
    __shared__ unsigned int sR;

    // ---- init LDS ----
    for (int i = tid; i < NBINS; i += BLOCK) hist[i] = 0u;
    for (int i = tid; i < NMASKW; i += BLOCK) mask[i] = 0u;
    if (tid == 0) { candcnt = 0u; suffixP[BLOCK] = 0u; }
    __syncthreads();

    // ---- pass 1: 4096-bin histogram of monotone key bin = floor(v*4096) ----
    const float4* g4 = (const float4*)g;
    for (int i = tid; i < NVEC; i += BLOCK) {
        float4 v = g4[i];
        int b0 = min((int)(v.x * 4096.0f), NBINS - 1);
        int b1 = min((int)(v.y * 4096.0f), NBINS - 1);
        int b2 = min((int)(v.z * 4096.0f), NBINS - 1);
        int b3 = min((int)(v.w * 4096.0f), NBINS - 1);
        atomicAdd(&hist[b0], 1u);
        atomicAdd(&hist[b1], 1u);
        atomicAdd(&hist[b2], 1u);
        atomicAdd(&hist[b3], 1u);
    }
    __syncthreads();

    // ---- suffix sums over 1024 groups of 4 bins (Hillis-Steele) ----
    {
        unsigned int s = hist[4 * tid] + hist[4 * tid + 1]
                       + hist[4 * tid + 2] + hist[4 * tid + 3];
        suffixP[tid] = s;
        __syncthreads();
        for (int off = 1; off < BLOCK; off <<= 1) {
            unsigned int v = suffixP[tid];
            if (tid + off < BLOCK) v += suffixP[tid + off];
            __syncthreads();
            suffixP[tid] = v;
            __syncthreads();
        }
    }

    // ---- find threshold bin B1 and residual rank r within it ----
    {
        unsigned int a  = suffixP[tid];
        unsigned int nx = suffixP[tid + 1];   // suffixP[1024] == 0
        if (a >= KSEL && nx < KSEL) {
            unsigned int cum = nx;
            for (int i = 3; i >= 0; --i) {
                unsigned int h = hist[4 * tid + i];
                cum += h;
                if (cum >= KSEL) {
                    sB1 = 4 * tid + i;
                    sR  = KSEL - (cum - h);   // how many to take from bin B1
                    break;
                }
            }
        }
    }
    __syncthreads();

    // ---- pass 2: set mask for bins > B1; compact bin == B1 candidates ----
    {
        const int B1 = sB1;
        for (int i = tid; i < NVEC; i += BLOCK) {
            float4 v = g4[i];
            int base = 4 * i;
            float vv[4] = {v.x, v.y, v.z, v.w};
            #pragma unroll
            for (int c = 0; c < 4; ++c) {
                int bin = min((int)(vv[c] * 4096.0f), NBINS - 1);
                if (bin > B1) {
                    int idx = base + c;
                    int p = idx % NPIX;
                    atomicOr(&mask[p >> 5], 1u << (p & 31));
                } else if (bin == B1) {
                    unsigned int c2 = atomicAdd(&candcnt, 1u);
                    if (c2 < MAXCAND) {
                        candkey[c2] = __float_as_uint(vv[c]); // nonneg: uint order == float order
                        candidx[c2] = (unsigned int)(base + c);
                    }
                }
            }
        }
    }
    __syncthreads();

    // ---- exact rank among candidates: (value desc, index asc) = jax.lax.top_k order ----
    {
        unsigned int n = candcnt < MAXCAND ? candcnt : MAXCAND;
        unsigned int r = sR;
        for (unsigned int j = tid; j < n; j += BLOCK) {
            unsigned int kj = candkey[j];
            unsigned int ij = candidx[j];
            unsigned int rank = 0;
            for (unsigned int i = 0; i < n; ++i) {
                unsigned int ki = candkey[i];
                rank += (ki > kj) || (ki == kj && candidx[i] < ij);
            }
            if (rank < r) {
                int p = (int)(ij % NPIX);
                atomicOr(&mask[p >> 5], 1u << (p & 31));
            }
        }
    }
    __syncthreads();

    // ---- output: masked copy of data ----
    {
        const float4* d4 = (const float4*)d;
        float4*       o4 = (float4*)o;
        for (int i = tid; i < NVEC; i += BLOCK) {
            float4 v = d4[i];
            int e = 4 * i;
            int p0 = e / 3, p1 = (e + 1) / 3, p2 = (e + 2) / 3, p3 = (e + 3) / 3;
            if ((mask[p0 >> 5] >> (p0 & 31)) & 1u) v.x = 0.0f;
            if ((mask[p1 >> 5] >> (p1 & 31)) & 1u) v.y = 0.0f;
            if ((mask[p2 >> 5] >> (p2 & 31)) & 1u) v.z = 0.0f;
            if ((mask[p3 >> 5] >> (p3 & 31)) & 1u) v.w = 0.0f;
            o4[i] = v;
        }
    }
}

extern "C" void kernel_launch(void* const* d_in, const int* in_sizes, int n_in,
                              void* d_out, int out_size, void* d_ws, size_t ws_size,
                              hipStream_t stream) {
    const float* data = (const float*)d_in[0];   // [256, 224, 224, 3] fp32
    const float* grad = (const float*)d_in[1];   // [256, 150528] fp32
    float* out = (float*)d_out;                  // [256, 224, 224, 3] fp32

    const int B = in_sizes[0] / NELEM;           // 256
    masked_model_kernel<<<B, BLOCK, 0, stream>>>(data, grad, out);
}